// Round 2
// baseline (1596.970 us; speedup 1.0000x reference)
//
// Round 1: fit workspace (436MB -> 160MB): JIT weight cvt (1 shared buffer),
// gram as bf16 in d_out, d_out triple-use (gram bf16 / xO f32 / final f32),
// PT aliases xAT+xBT, xosm aliases xbf, y5 aliases xC.
// Predicted: pass, absmax ~0.02-0.06, ~1.3-1.4ms (7 GEMMs @ ~850 TF).
#include <hip/hip_runtime.h>
#include <hip/hip_bf16.h>

#define DD 4096
#define SS 2048
#define BB 2

typedef float f32x4 __attribute__((ext_vector_type(4)));
typedef short bf16x8 __attribute__((ext_vector_type(8)));

__device__ __forceinline__ unsigned short f2b(float f) {
  unsigned int u = __float_as_uint(f);
  u += 0x7fffu + ((u >> 16) & 1u);
  return (unsigned short)(u >> 16);
}
__device__ __forceinline__ float b2f(unsigned short h) {
  return __uint_as_float((unsigned int)h << 16);
}

// async global->LDS, 16B per lane. LDS dest: wave-uniform base + lane*16.
__device__ __forceinline__ void gll16(const unsigned short* g, unsigned short* l) {
  __builtin_amdgcn_global_load_lds(
      (const __attribute__((address_space(1))) unsigned int*)g,
      (__attribute__((address_space(3))) unsigned int*)l, 16, 0, 0);
}

// ---------------------------------------------------------------------------
// gemm_bt: C[m][n] = sum_k A[m][k] * B[n][k]   (A: MxK row-major, B: NxK row-major)
// 128x128 tile, BK=32, 4 waves, each wave 64x64 (4x4 fragments of 16x16x32).
// EPI: 0 = store bf16, 1 = store f32, 2 = store bf16( R[idx] + silu(acc) )
// ---------------------------------------------------------------------------
template <int EPI>
__global__ __launch_bounds__(256)
void gemm_bt(const unsigned short* __restrict__ A,
             const unsigned short* __restrict__ B,
             void* __restrict__ Cv,
             const float* __restrict__ R,
             int M, int N, int K,
             long long sA, long long sB, long long sC) {
  __shared__ __align__(16) unsigned short lA[128 * 32];
  __shared__ __align__(16) unsigned short lB[128 * 32];

  const int tid = threadIdx.x;
  const int lane = tid & 63;
  const int wr = (tid >> 6) >> 1;
  const int wc = (tid >> 6) & 1;
  const int bm = blockIdx.y, bn = blockIdx.x, bz = blockIdx.z;

  const unsigned short* Ab = A + (size_t)bz * sA;
  const unsigned short* Bb = B + (size_t)bz * sB;

  const int i0 = tid, i1 = tid + 256;
  const int r0i = i0 >> 2, c0i = (i0 & 3) * 8;
  const int r1i = i1 >> 2, c1i = (i1 & 3) * 8;

  const unsigned short* gA0 = Ab + (size_t)(bm * 128 + r0i) * K + c0i;
  const unsigned short* gA1 = Ab + (size_t)(bm * 128 + r1i) * K + c1i;
  const unsigned short* gB0 = Bb + (size_t)(bn * 128 + r0i) * K + c0i;
  const unsigned short* gB1 = Bb + (size_t)(bn * 128 + r1i) * K + c1i;
  unsigned short* dA0 = &lA[i0 * 8];
  unsigned short* dA1 = &lA[i1 * 8];
  unsigned short* dB0 = &lB[i0 * 8];
  unsigned short* dB1 = &lB[i1 * 8];

  f32x4 acc[4][4] = {};

  const int aoff = (wr * 64 + (lane & 15)) * 32 + (lane >> 4) * 8;
  const int boff = (wc * 64 + (lane & 15)) * 32 + (lane >> 4) * 8;

  for (int kt = 0; kt < K; kt += 32) {
    gll16(gA0 + kt, dA0);
    gll16(gA1 + kt, dA1);
    gll16(gB0 + kt, dB0);
    gll16(gB1 + kt, dB1);
    __syncthreads();  // drains vmcnt(0): LDS tiles ready
    bf16x8 af[4], bfv[4];
#pragma unroll
    for (int m = 0; m < 4; ++m) af[m] = *(const bf16x8*)&lA[aoff + m * 512];
#pragma unroll
    for (int n = 0; n < 4; ++n) bfv[n] = *(const bf16x8*)&lB[boff + n * 512];
#pragma unroll
    for (int m = 0; m < 4; ++m)
#pragma unroll
      for (int n = 0; n < 4; ++n)
        acc[m][n] = __builtin_amdgcn_mfma_f32_16x16x32_bf16(af[m], bfv[n], acc[m][n], 0, 0, 0);
    __syncthreads();
  }

  // C/D layout (m89/m91 verified): col = lane&15, row = (lane>>4)*4 + reg
  const int row0 = bm * 128 + wr * 64 + (lane >> 4) * 4;
  const int col0 = bn * 128 + wc * 64 + (lane & 15);

  if constexpr (EPI == 1) {
    float* C = (float*)Cv + (size_t)bz * sC;
#pragma unroll
    for (int m = 0; m < 4; ++m)
#pragma unroll
      for (int j = 0; j < 4; ++j) {
        size_t ro = (size_t)(row0 + m * 16 + j) * N;
#pragma unroll
        for (int n = 0; n < 4; ++n) C[ro + col0 + n * 16] = acc[m][n][j];
      }
  } else if constexpr (EPI == 0) {
    unsigned short* C = (unsigned short*)Cv + (size_t)bz * sC;
#pragma unroll
    for (int m = 0; m < 4; ++m)
#pragma unroll
      for (int j = 0; j < 4; ++j) {
        size_t ro = (size_t)(row0 + m * 16 + j) * N;
#pragma unroll
        for (int n = 0; n < 4; ++n) C[ro + col0 + n * 16] = f2b(acc[m][n][j]);
      }
  } else {
    unsigned short* C = (unsigned short*)Cv + (size_t)bz * sC;
#pragma unroll
    for (int m = 0; m < 4; ++m)
#pragma unroll
      for (int j = 0; j < 4; ++j) {
        size_t ro = (size_t)(row0 + m * 16 + j) * N;
#pragma unroll
        for (int n = 0; n < 4; ++n) {
          size_t idx = ro + col0 + n * 16;
          float v = acc[m][n][j];
          float s = v / (1.f + __expf(-v));  // silu
          C[idx] = f2b(R[idx] + s);
        }
      }
  }
}

// ---------------------------------------------------------------------------
__device__ __forceinline__ float wred_max(float v) {
#pragma unroll
  for (int o = 32; o > 0; o >>= 1) v = fmaxf(v, __shfl_xor(v, o, 64));
  return v;
}
__device__ __forceinline__ float wred_sum(float v) {
#pragma unroll
  for (int o = 32; o > 0; o >>= 1) v += __shfl_xor(v, o, 64);
  return v;
}

// per-row max & sum(exp(x-max)) over 4096 bf16; one block per row
__global__ __launch_bounds__(256)
void row_stats_bf16(const unsigned short* __restrict__ X, float* __restrict__ smax,
                    float* __restrict__ ssum) {
  const size_t row = blockIdx.x;
  const uint4* p = (const uint4*)(X + row * DD);  // 512 x 16B
  const int t = threadIdx.x;
  uint4 u[2];
  u[0] = p[t];
  u[1] = p[t + 256];
  float fv[16];
#pragma unroll
  for (int q = 0; q < 2; ++q) {
    const unsigned int* w = (const unsigned int*)&u[q];
#pragma unroll
    for (int j = 0; j < 4; ++j) {
      fv[q * 8 + j * 2 + 0] = b2f((unsigned short)(w[j] & 0xFFFFu));
      fv[q * 8 + j * 2 + 1] = b2f((unsigned short)(w[j] >> 16));
    }
  }
  float m = -1e30f;
#pragma unroll
  for (int i = 0; i < 16; ++i) m = fmaxf(m, fv[i]);
  __shared__ float rb[8];
  float wm = wred_max(m);
  if ((t & 63) == 0) rb[t >> 6] = wm;
  __syncthreads();
  const float gm = fmaxf(fmaxf(rb[0], rb[1]), fmaxf(rb[2], rb[3]));
  float s = 0.f;
#pragma unroll
  for (int i = 0; i < 16; ++i) s += __expf(fv[i] - gm);
  float wsum = wred_sum(s);
  if ((t & 63) == 0) rb[4 + (t >> 6)] = wsum;
  __syncthreads();
  if (t == 0) { smax[row] = gm; ssum[row] = rb[4] + rb[5] + rb[6] + rb[7]; }
}

// exp/normalize bf16 Gram logits, write TRANSPOSED bf16: PT[b][e][d]
__global__ __launch_bounds__(256)
void exp_transpose_bf16(const unsigned short* __restrict__ X,
                        const float* __restrict__ smax,
                        const float* __restrict__ ssum,
                        unsigned short* __restrict__ PT) {
  const int b = blockIdx.z;
  const int d0 = blockIdx.y * 64;
  const int e0 = blockIdx.x * 64;
  __shared__ unsigned short lt[64][72];
  const int t = threadIdx.x;
  const int tr = t >> 4;
  const int tc = (t & 15) * 4;
  const unsigned short* Xb = X + (size_t)b * DD * DD;
#pragma unroll
  for (int rr = 0; rr < 64; rr += 16) {
    const int dd = rr + tr;
    ushort4 v = *(const ushort4*)&Xb[(size_t)(d0 + dd) * DD + e0 + tc];
    const float mx = smax[(size_t)b * DD + d0 + dd];
    const float inv = 1.f / ssum[(size_t)b * DD + d0 + dd];
    lt[dd][tc + 0] = f2b(__expf(b2f(v.x) - mx) * inv);
    lt[dd][tc + 1] = f2b(__expf(b2f(v.y) - mx) * inv);
    lt[dd][tc + 2] = f2b(__expf(b2f(v.z) - mx) * inv);
    lt[dd][tc + 3] = f2b(__expf(b2f(v.w) - mx) * inv);
  }
  __syncthreads();
  unsigned short* Pb = PT + (size_t)b * DD * DD;
#pragma unroll
  for (int rr = 0; rr < 64; rr += 16) {
    const int ee = rr + tr;
    ushort4 o;
    o.x = lt[tc + 0][ee];
    o.y = lt[tc + 1][ee];
    o.z = lt[tc + 2][ee];
    o.w = lt[tc + 3][ee];
    *(ushort4*)&Pb[(size_t)(e0 + ee) * DD + d0 + tc] = o;
  }
}

// full row softmax f32 -> bf16, one block per row of 4096
__global__ __launch_bounds__(256)
void row_softmax_bf16(const float* __restrict__ X, unsigned short* __restrict__ Y) {
  const size_t row = blockIdx.x;
  const float4* p = (const float4*)(X + row * DD);
  const int t = threadIdx.x;
  float4 v[4];
  float m = -1e30f;
#pragma unroll
  for (int q = 0; q < 4; ++q) {
    v[q] = p[q * 256 + t];
    m = fmaxf(m, fmaxf(fmaxf(v[q].x, v[q].y), fmaxf(v[q].z, v[q].w)));
  }
  __shared__ float rb[8];
  float wm = wred_max(m);
  if ((t & 63) == 0) rb[t >> 6] = wm;
  __syncthreads();
  const float gm = fmaxf(fmaxf(rb[0], rb[1]), fmaxf(rb[2], rb[3]));
  float s = 0.f;
#pragma unroll
  for (int q = 0; q < 4; ++q) {
    v[q].x = __expf(v[q].x - gm); v[q].y = __expf(v[q].y - gm);
    v[q].z = __expf(v[q].z - gm); v[q].w = __expf(v[q].w - gm);
    s += v[q].x + v[q].y + v[q].z + v[q].w;
  }
  float wsum = wred_sum(s);
  if ((t & 63) == 0) rb[4 + (t >> 6)] = wsum;
  __syncthreads();
  const float inv = 1.f / (rb[4] + rb[5] + rb[6] + rb[7]);
  ushort4* yo = (ushort4*)(Y + row * DD);
#pragma unroll
  for (int q = 0; q < 4; ++q) {
    ushort4 o;
    o.x = f2b(v[q].x * inv); o.y = f2b(v[q].y * inv);
    o.z = f2b(v[q].z * inv); o.w = f2b(v[q].w * inv);
    yo[q * 256 + t] = o;
  }
}

// f32 -> bf16 elementwise (n4 = count/4)
__global__ __launch_bounds__(256)
void cvt_bf16(const float* __restrict__ X, unsigned short* __restrict__ Y, size_t n4) {
  size_t i = (size_t)blockIdx.x * 256 + threadIdx.x;
  const size_t stride = (size_t)gridDim.x * 256;
  for (; i < n4; i += stride) {
    float4 v = ((const float4*)X)[i];
    ushort4 o;
    o.x = f2b(v.x); o.y = f2b(v.y); o.z = f2b(v.z); o.w = f2b(v.w);
    ((ushort4*)Y)[i] = o;
  }
}

__global__ void ws_sentinel(float* o, float v) { o[0] = v; }

// ---------------------------------------------------------------------------
extern "C" void kernel_launch(void* const* d_in, const int* in_sizes, int n_in,
                              void* d_out, int out_size, void* d_ws, size_t ws_size,
                              hipStream_t stream) {
  const float* x = (const float*)d_in[0];
  const float* W[5] = {(const float*)d_in[1], (const float*)d_in[2],
                       (const float*)d_in[3], (const float*)d_in[4],
                       (const float*)d_in[5]};
  float* out = (float*)d_out;
  char* ws = (char*)d_ws;

  const size_t WBb = (size_t)DD * DD * 2;  // 33,554,432 bytes
  const size_t NEEDED = 5 * WBb + 2 * (size_t)BB * DD * sizeof(float);
  if (ws_size < NEEDED) {  // sentinel now reports ws_size via absmax
    ws_sentinel<<<1, 1, 0, stream>>>(out, (float)ws_size);
    return;
  }

  unsigned short* xbf  = (unsigned short*)(ws + 0 * WBb);  // later: xosm
  unsigned short* wbuf = (unsigned short*)(ws + 1 * WBb);  // JIT weight cvt
  unsigned short* xAT  = (unsigned short*)(ws + 2 * WBb);  // later: PT (spans xAT+xBT)
  unsigned short* xBT  = (unsigned short*)(ws + 3 * WBb);
  unsigned short* xC   = (unsigned short*)(ws + 4 * WBb);  // later: y5
  float* smax = (float*)(ws + 5 * WBb);
  float* ssum = smax + (size_t)BB * DD;

  unsigned short* gram = (unsigned short*)d_out;  // bf16 Gram logits (= 64MB exactly)
  unsigned short* PT   = xAT;                      // P^T bf16 [2][4096][4096]
  float* xO            = (float*)d_out;            // f32 logits (gram dead by then)
  unsigned short* xosm = xbf;
  unsigned short* y5   = xC;

  const size_t n4 = (size_t)DD * DD / 4;
  cvt_bf16<<<2048, 256, 0, stream>>>(x, xbf, n4);

  // GEMM1a: xAT[b][e][s] = sum_d W1[e,d] * x[b,s,d]
  cvt_bf16<<<2048, 256, 0, stream>>>(W[0], wbuf, n4);
  gemm_bt<0><<<dim3(SS / 128, DD / 128, BB), 256, 0, stream>>>(
      wbuf, xbf, xAT, nullptr, DD, SS, DD, 0LL, (long long)SS * DD, (long long)DD * SS);
  // GEMM1b: xBT
  cvt_bf16<<<2048, 256, 0, stream>>>(W[1], wbuf, n4);
  gemm_bt<0><<<dim3(SS / 128, DD / 128, BB), 256, 0, stream>>>(
      wbuf, xbf, xBT, nullptr, DD, SS, DD, 0LL, (long long)SS * DD, (long long)DD * SS);
  // GEMM1c: xC[n][e] = sum_d x[n,d] * W3[e,d]
  cvt_bf16<<<2048, 256, 0, stream>>>(W[2], wbuf, n4);
  gemm_bt<0><<<dim3(DD / 128, (BB * SS) / 128, 1), 256, 0, stream>>>(
      xbf, wbuf, xC, nullptr, BB * SS, DD, DD, 0LL, 0LL, 0LL);
  // GEMM2 (Gram): gram[b][d][e] = sum_s xAT[b,d,s] * xBT[b,e,s] -> bf16 in d_out
  gemm_bt<0><<<dim3(DD / 128, DD / 128, BB), 256, 0, stream>>>(
      xAT, xBT, gram, nullptr, DD, DD, SS, (long long)DD * SS, (long long)DD * SS,
      (long long)DD * DD);
  // softmax over e, transposed bf16 PT[b][e][d] (overwrites xAT+xBT)
  row_stats_bf16<<<BB * DD, 256, 0, stream>>>(gram, smax, ssum);
  exp_transpose_bf16<<<dim3(DD / 64, DD / 64, BB), 256, 0, stream>>>(gram, smax, ssum, PT);
  // GEMM3: xO[b][s][e] = sum_d xC[b,s,d] * PT[b,e,d]  (f32, overwrites gram in d_out)
  gemm_bt<1><<<dim3(DD / 128, SS / 128, BB), 256, 0, stream>>>(
      xC, PT, xO, nullptr, SS, DD, DD, (long long)SS * DD, (long long)DD * DD,
      (long long)SS * DD);
  // second softmax (rows of 4096) -> bf16 xosm (overwrites xbf)
  row_softmax_bf16<<<BB * SS, 256, 0, stream>>>(xO, xosm);
  // GEMM4: y5 = bf16( x + silu(xosm @ W4^T) )  (overwrites xC)
  cvt_bf16<<<2048, 256, 0, stream>>>(W[3], wbuf, n4);
  gemm_bt<2><<<dim3(DD / 128, (BB * SS) / 128, 1), 256, 0, stream>>>(
      xosm, wbuf, y5, x, BB * SS, DD, DD, 0LL, 0LL, 0LL);
  // GEMM5: out = y5 @ W5^T  (f32, final)
  cvt_bf16<<<2048, 256, 0, stream>>>(W[4], wbuf, n4);
  gemm_bt<1><<<dim3(DD / 128, (BB * SS) / 128, 1), 256, 0, stream>>>(
      y5, wbuf, out, nullptr, BB * SS, DD, DD, 0LL, 0LL, 0LL);
}

// Round 3
// 1042.260 us; speedup vs baseline: 1.5322x; 1.5322x over previous
//
// Round 2: port GEMMs to 256x256 deep-pipelined structure (T1 XCD swizzle,
// T2 subtiled LDS swizzle, T3/T4 counted-vmcnt ring-4 pipeline, T5 setprio).
// BK=32, 8 waves (2x4), 2 phases/K-tile, 131KB dynamic LDS, prefetch depth 2 K-tiles.
// Predicted: GEMM 240->~90us each, MfmaUtil ~55-62%, total ~800us.
#include <hip/hip_runtime.h>
#include <hip/hip_bf16.h>

#define DD 4096
#define SS 2048
#define BB 2

typedef float f32x4 __attribute__((ext_vector_type(4)));
typedef short bf16x8 __attribute__((ext_vector_type(8)));

__device__ __forceinline__ unsigned short f2b(float f) {
  unsigned int u = __float_as_uint(f);
  u += 0x7fffu + ((u >> 16) & 1u);
  return (unsigned short)(u >> 16);
}
__device__ __forceinline__ float b2f(unsigned short h) {
  return __uint_as_float((unsigned int)h << 16);
}

// async global->LDS, 16B/lane. HW: lds dest = wave-uniform base + lane*16.
__device__ __forceinline__ void gll16(const unsigned short* g, unsigned short* l) {
  __builtin_amdgcn_global_load_lds(
      (const __attribute__((address_space(1))) unsigned int*)g,
      (__attribute__((address_space(3))) unsigned int*)l, 16, 0, 0);
}

#define MEMFENCE asm volatile("" ::: "memory")

// ---------------------------------------------------------------------------
// gemm256: C[m][n] = sum_k A[m][k]*B[n][k]; 256x256 tile, BK=32, ring-4 LDS.
// LDS layout per slot: A then B, each 16 row-groups x [16][32] bf16 subtiles
// (1KB contiguous each), st-swizzle: byte ^= ((byte>>9)&1)<<5 within subtile.
// EPI: 0 = bf16 store, 1 = f32 store, 2 = bf16( R + silu(acc) )
// ---------------------------------------------------------------------------
template <int EPI>
__global__ __launch_bounds__(512, 2)
void gemm256(const unsigned short* __restrict__ A,
             const unsigned short* __restrict__ B,
             void* __restrict__ Cv,
             const float* __restrict__ R,
             int GM, int GN,
             int N, int K,
             long long sA, long long sB, long long sC) {
  extern __shared__ __align__(16) char lds[];
  const int tid = threadIdx.x;
  const int lane = tid & 63;
  const int wid = tid >> 6;  // 0..7
  const int wm = wid >> 2;   // 0..1
  const int wn = wid & 3;    // 0..3

  // T1: bijective XCD swizzle (launcher guarantees gridDim.x % 8 == 0)
  const int nwg = gridDim.x;
  const int cpx = nwg >> 3;
  const int wg = ((int)blockIdx.x & 7) * cpx + ((int)blockIdx.x >> 3);
  const int bz = wg / (GM * GN);
  const int rem = wg - bz * (GM * GN);
  const int bm = rem / GN;
  const int bn = rem - bm * GN;

  const unsigned short* Ab = A + (size_t)bz * sA + (size_t)bm * 256 * K;
  const unsigned short* Bb = B + (size_t)bz * sB + (size_t)bn * 256 * K;

  // ---- staging addresses (T2: inverse-swizzled global source, linear LDS dest)
  const int lsw = lane ^ (((lane >> 5) & 1) << 1);
  const int srow = lsw >> 2;          // 0..15 within row-group
  const int scol = (lsw & 3) * 8;     // k elements 0/8/16/24
  const unsigned short* gA0 = Ab + (size_t)(wid * 16 + srow) * K + scol;
  const unsigned short* gA1 = gA0 + (size_t)128 * K;  // row-group wid+8
  const unsigned short* gB0 = Bb + (size_t)(wid * 16 + srow) * K + scol;
  const unsigned short* gB1 = gB0 + (size_t)128 * K;

  // ---- fragment read offset within subtile (bytes), swizzled
  const int r16 = lane & 15;
  const int c16 = ((lane >> 4) * 16) ^ ((r16 & 8) << 2);  // ^32 when r16>=8
  const int fro = r16 * 64 + c16;

  f32x4 acc[8][4] = {};
  const int NT = K >> 5;  // K-tiles of 32

  // ---- prologue: stage tiles 0 and 1 into slots 0,1
  {
    char* s0 = lds;
    char* s1 = lds + 32768;
    gll16(gA0, (unsigned short*)(s0 + wid * 1024));
    gll16(gA1, (unsigned short*)(s0 + (wid + 8) * 1024));
    gll16(gB0, (unsigned short*)(s0 + 16384 + wid * 1024));
    gll16(gB1, (unsigned short*)(s0 + 16384 + (wid + 8) * 1024));
    gll16(gA0 + 32, (unsigned short*)(s1 + wid * 1024));
    gll16(gA1 + 32, (unsigned short*)(s1 + (wid + 8) * 1024));
    gll16(gB0 + 32, (unsigned short*)(s1 + 16384 + wid * 1024));
    gll16(gB1 + 32, (unsigned short*)(s1 + 16384 + (wid + 8) * 1024));
  }
  asm volatile("s_waitcnt vmcnt(4)" ::: "memory");  // tile 0 landed; tile 1 in flight
  __builtin_amdgcn_s_barrier();
  MEMFENCE;

  for (int T = 0; T < NT; ++T) {
    const char* lA = lds + (size_t)((T & 3) * 32768);
    const char* lB = lA + 16384;
    char* ps = lds + (size_t)(((T + 2) & 3) * 32768);
    const bool doStage = (T + 2 < NT);
    const int kOff = (T + 2) * 32;

    // ===== phase A: quadrant m0-3 x n0-3 =====
    bf16x8 bf[4], af[4];
#pragma unroll
    for (int n = 0; n < 4; ++n)
      bf[n] = *(const bf16x8*)(lB + (wn * 4 + n) * 1024 + fro);
#pragma unroll
    for (int m = 0; m < 4; ++m)
      af[m] = *(const bf16x8*)(lA + (wm * 8 + m) * 1024 + fro);
    if (doStage) {
      gll16(gA0 + kOff, (unsigned short*)(ps + wid * 1024));
      gll16(gA1 + kOff, (unsigned short*)(ps + (wid + 8) * 1024));
    }
    MEMFENCE;
    __builtin_amdgcn_s_barrier();
    MEMFENCE;
    __builtin_amdgcn_s_setprio(1);
#pragma unroll
    for (int m = 0; m < 4; ++m)
#pragma unroll
      for (int n = 0; n < 4; ++n)
        acc[m][n] = __builtin_amdgcn_mfma_f32_16x16x32_bf16(af[m], bf[n], acc[m][n], 0, 0, 0);
    __builtin_amdgcn_s_setprio(0);
    MEMFENCE;
    __builtin_amdgcn_s_barrier();
    MEMFENCE;

    // ===== phase B: quadrant m4-7 x n0-3 =====
#pragma unroll
    for (int m = 0; m < 4; ++m)
      af[m] = *(const bf16x8*)(lA + (wm * 8 + 4 + m) * 1024 + fro);
    if (doStage) {
      gll16(gB0 + kOff, (unsigned short*)(ps + 16384 + wid * 1024));
      gll16(gB1 + kOff, (unsigned short*)(ps + 16384 + (wid + 8) * 1024));
    }
    MEMFENCE;
    __builtin_amdgcn_s_barrier();
    MEMFENCE;
    __builtin_amdgcn_s_setprio(1);
#pragma unroll
    for (int m = 0; m < 4; ++m)
#pragma unroll
      for (int n = 0; n < 4; ++n)
        acc[m + 4][n] =
            __builtin_amdgcn_mfma_f32_16x16x32_bf16(af[m], bf[n], acc[m + 4][n], 0, 0, 0);
    __builtin_amdgcn_s_setprio(0);
    // T4: counted drain — tile T+1 must be resident for next iteration.
    if (T + 1 < NT) {
      if (doStage) asm volatile("s_waitcnt vmcnt(4)" ::: "memory");
      else         asm volatile("s_waitcnt vmcnt(0)" ::: "memory");
    }
    MEMFENCE;
    __builtin_amdgcn_s_barrier();
    MEMFENCE;
  }

  // ---- epilogue: C/D layout col=lane&15, row=(lane>>4)*4+j
  const int row0 = bm * 256 + wm * 128 + (lane >> 4) * 4;
  const int col0 = bn * 256 + wn * 64 + (lane & 15);

  if constexpr (EPI == 1) {
    float* C = (float*)Cv + (size_t)bz * sC;
#pragma unroll
    for (int m = 0; m < 8; ++m)
#pragma unroll
      for (int j = 0; j < 4; ++j) {
        size_t ro = (size_t)(row0 + m * 16 + j) * N;
#pragma unroll
        for (int n = 0; n < 4; ++n) C[ro + col0 + n * 16] = acc[m][n][j];
      }
  } else if constexpr (EPI == 0) {
    unsigned short* C = (unsigned short*)Cv + (size_t)bz * sC;
#pragma unroll
    for (int m = 0; m < 8; ++m)
#pragma unroll
      for (int j = 0; j < 4; ++j) {
        size_t ro = (size_t)(row0 + m * 16 + j) * N;
#pragma unroll
        for (int n = 0; n < 4; ++n) C[ro + col0 + n * 16] = f2b(acc[m][n][j]);
      }
  } else {
    unsigned short* C = (unsigned short*)Cv + (size_t)bz * sC;
#pragma unroll
    for (int m = 0; m < 8; ++m)
#pragma unroll
      for (int j = 0; j < 4; ++j) {
        size_t ro = (size_t)(row0 + m * 16 + j) * N;
#pragma unroll
        for (int n = 0; n < 4; ++n) {
          size_t idx = ro + col0 + n * 16;
          float v = acc[m][n][j];
          float s = v / (1.f + __expf(-v));
          C[idx] = f2b(R[idx] + s);
        }
      }
  }
}

// ---------------------------------------------------------------------------
__device__ __forceinline__ float wred_max(float v) {
#pragma unroll
  for (int o = 32; o > 0; o >>= 1) v = fmaxf(v, __shfl_xor(v, o, 64));
  return v;
}
__device__ __forceinline__ float wred_sum(float v) {
#pragma unroll
  for (int o = 32; o > 0; o >>= 1) v += __shfl_xor(v, o, 64);
  return v;
}

__global__ __launch_bounds__(256)
void row_stats_bf16(const unsigned short* __restrict__ X, float* __restrict__ smax,
                    float* __restrict__ ssum) {
  const size_t row = blockIdx.x;
  const uint4* p = (const uint4*)(X + row * DD);
  const int t = threadIdx.x;
  uint4 u[2];
  u[0] = p[t];
  u[1] = p[t + 256];
  float fv[16];
#pragma unroll
  for (int q = 0; q < 2; ++q) {
    const unsigned int* w = (const unsigned int*)&u[q];
#pragma unroll
    for (int j = 0; j < 4; ++j) {
      fv[q * 8 + j * 2 + 0] = b2f((unsigned short)(w[j] & 0xFFFFu));
      fv[q * 8 + j * 2 + 1] = b2f((unsigned short)(w[j] >> 16));
    }
  }
  float m = -1e30f;
#pragma unroll
  for (int i = 0; i < 16; ++i) m = fmaxf(m, fv[i]);
  __shared__ float rb[8];
  float wm = wred_max(m);
  if ((t & 63) == 0) rb[t >> 6] = wm;
  __syncthreads();
  const float gm = fmaxf(fmaxf(rb[0], rb[1]), fmaxf(rb[2], rb[3]));
  float s = 0.f;
#pragma unroll
  for (int i = 0; i < 16; ++i) s += __expf(fv[i] - gm);
  float wsum = wred_sum(s);
  if ((t & 63) == 0) rb[4 + (t >> 6)] = wsum;
  __syncthreads();
  if (t == 0) { smax[row] = gm; ssum[row] = rb[4] + rb[5] + rb[6] + rb[7]; }
}

__global__ __launch_bounds__(256)
void exp_transpose_bf16(const unsigned short* __restrict__ X,
                        const float* __restrict__ smax,
                        const float* __restrict__ ssum,
                        unsigned short* __restrict__ PT) {
  const int b = blockIdx.z;
  const int d0 = blockIdx.y * 64;
  const int e0 = blockIdx.x * 64;
  __shared__ unsigned short lt[64][72];
  const int t = threadIdx.x;
  const int tr = t >> 4;
  const int tc = (t & 15) * 4;
  const unsigned short* Xb = X + (size_t)b * DD * DD;
#pragma unroll
  for (int rr = 0; rr < 64; rr += 16) {
    const int dd = rr + tr;
    ushort4 v = *(const ushort4*)&Xb[(size_t)(d0 + dd) * DD + e0 + tc];
    const float mx = smax[(size_t)b * DD + d0 + dd];
    const float inv = 1.f / ssum[(size_t)b * DD + d0 + dd];
    lt[dd][tc + 0] = f2b(__expf(b2f(v.x) - mx) * inv);
    lt[dd][tc + 1] = f2b(__expf(b2f(v.y) - mx) * inv);
    lt[dd][tc + 2] = f2b(__expf(b2f(v.z) - mx) * inv);
    lt[dd][tc + 3] = f2b(__expf(b2f(v.w) - mx) * inv);
  }
  __syncthreads();
  unsigned short* Pb = PT + (size_t)b * DD * DD;
#pragma unroll
  for (int rr = 0; rr < 64; rr += 16) {
    const int ee = rr + tr;
    ushort4 o;
    o.x = lt[tc + 0][ee];
    o.y = lt[tc + 1][ee];
    o.z = lt[tc + 2][ee];
    o.w = lt[tc + 3][ee];
    *(ushort4*)&Pb[(size_t)(e0 + ee) * DD + d0 + tc] = o;
  }
}

__global__ __launch_bounds__(256)
void row_softmax_bf16(const float* __restrict__ X, unsigned short* __restrict__ Y) {
  const size_t row = blockIdx.x;
  const float4* p = (const float4*)(X + row * DD);
  const int t = threadIdx.x;
  float4 v[4];
  float m = -1e30f;
#pragma unroll
  for (int q = 0; q < 4; ++q) {
    v[q] = p[q * 256 + t];
    m = fmaxf(m, fmaxf(fmaxf(v[q].x, v[q].y), fmaxf(v[q].z, v[q].w)));
  }
  __shared__ float rb[8];
  float wm = wred_max(m);
  if ((t & 63) == 0) rb[t >> 6] = wm;
  __syncthreads();
  const float gm = fmaxf(fmaxf(rb[0], rb[1]), fmaxf(rb[2], rb[3]));
  float s = 0.f;
#pragma unroll
  for (int q = 0; q < 4; ++q) {
    v[q].x = __expf(v[q].x - gm); v[q].y = __expf(v[q].y - gm);
    v[q].z = __expf(v[q].z - gm); v[q].w = __expf(v[q].w - gm);
    s += v[q].x + v[q].y + v[q].z + v[q].w;
  }
  float wsum = wred_sum(s);
  if ((t & 63) == 0) rb[4 + (t >> 6)] = wsum;
  __syncthreads();
  const float inv = 1.f / (rb[4] + rb[5] + rb[6] + rb[7]);
  ushort4* yo = (ushort4*)(Y + row * DD);
#pragma unroll
  for (int q = 0; q < 4; ++q) {
    ushort4 o;
    o.x = f2b(v[q].x * inv); o.y = f2b(v[q].y * inv);
    o.z = f2b(v[q].z * inv); o.w = f2b(v[q].w * inv);
    yo[q * 256 + t] = o;
  }
}

__global__ __launch_bounds__(256)
void cvt_bf16(const float* __restrict__ X, unsigned short* __restrict__ Y, size_t n4) {
  size_t i = (size_t)blockIdx.x * 256 + threadIdx.x;
  const size_t stride = (size_t)gridDim.x * 256;
  for (; i < n4; i += stride) {
    float4 v = ((const float4*)X)[i];
    ushort4 o;
    o.x = f2b(v.x); o.y = f2b(v.y); o.z = f2b(v.z); o.w = f2b(v.w);
    ((ushort4*)Y)[i] = o;
  }
}

__global__ void ws_sentinel(float* o, float v) { o[0] = v; }

// ---------------------------------------------------------------------------
extern "C" void kernel_launch(void* const* d_in, const int* in_sizes, int n_in,
                              void* d_out, int out_size, void* d_ws, size_t ws_size,
                              hipStream_t stream) {
  const float* x = (const float*)d_in[0];
  const float* W[5] = {(const float*)d_in[1], (const float*)d_in[2],
                       (const float*)d_in[3], (const float*)d_in[4],
                       (const float*)d_in[5]};
  float* out = (float*)d_out;
  char* ws = (char*)d_ws;

  const size_t WBb = (size_t)DD * DD * 2;
  const size_t NEEDED = 5 * WBb + 2 * (size_t)BB * DD * sizeof(float);
  if (ws_size < NEEDED) {
    ws_sentinel<<<1, 1, 0, stream>>>(out, (float)ws_size);
    return;
  }

  const int LDSB = 131072;
  hipFuncSetAttribute(reinterpret_cast<const void*>(gemm256<0>),
                      hipFuncAttributeMaxDynamicSharedMemorySize, LDSB);
  hipFuncSetAttribute(reinterpret_cast<const void*>(gemm256<1>),
                      hipFuncAttributeMaxDynamicSharedMemorySize, LDSB);
  hipFuncSetAttribute(reinterpret_cast<const void*>(gemm256<2>),
                      hipFuncAttributeMaxDynamicSharedMemorySize, LDSB);

  unsigned short* xbf  = (unsigned short*)(ws + 0 * WBb);
  unsigned short* wbuf = (unsigned short*)(ws + 1 * WBb);
  unsigned short* xAT  = (unsigned short*)(ws + 2 * WBb);
  unsigned short* xBT  = (unsigned short*)(ws + 3 * WBb);
  unsigned short* xC   = (unsigned short*)(ws + 4 * WBb);
  float* smax = (float*)(ws + 5 * WBb);
  float* ssum = smax + (size_t)BB * DD;

  unsigned short* gram = (unsigned short*)d_out;
  unsigned short* PT   = xAT;
  float* xO            = (float*)d_out;
  unsigned short* xosm = xbf;
  unsigned short* y5   = xC;

  const size_t n4 = (size_t)DD * DD / 4;
  cvt_bf16<<<2048, 256, 0, stream>>>(x, xbf, n4);

  // GEMM1a: xAT[b][e][s] = sum_d W1[e,d]*x[b,s,d]   M=4096,N=2048,K=4096,z=2
  cvt_bf16<<<2048, 256, 0, stream>>>(W[0], wbuf, n4);
  gemm256<0><<<16 * 8 * BB, 512, LDSB, stream>>>(
      wbuf, xbf, xAT, nullptr, 16, 8, SS, DD, 0LL, (long long)SS * DD, (long long)DD * SS);
  // GEMM1b: xBT
  cvt_bf16<<<2048, 256, 0, stream>>>(W[1], wbuf, n4);
  gemm256<0><<<16 * 8 * BB, 512, LDSB, stream>>>(
      wbuf, xbf, xBT, nullptr, 16, 8, SS, DD, 0LL, (long long)SS * DD, (long long)DD * SS);
  // GEMM1c: xC[n][e] = sum_d x[n,d]*W3[e,d]   M=4096,N=4096,K=4096
  cvt_bf16<<<2048, 256, 0, stream>>>(W[2], wbuf, n4);
  gemm256<0><<<16 * 16, 512, LDSB, stream>>>(
      xbf, wbuf, xC, nullptr, 16, 16, DD, DD, 0LL, 0LL, 0LL);
  // GEMM2 (Gram): gram[b][d][e] = sum_s xAT[b,d,s]*xBT[b,e,s]  K=2048, bf16 out
  gemm256<0><<<16 * 16 * BB, 512, LDSB, stream>>>(
      xAT, xBT, gram, nullptr, 16, 16, DD, SS, (long long)DD * SS, (long long)DD * SS,
      (long long)DD * DD);
  // Gram softmax over e -> transposed bf16 PT[b][e][d]
  row_stats_bf16<<<BB * DD, 256, 0, stream>>>(gram, smax, ssum);
  exp_transpose_bf16<<<dim3(DD / 64, DD / 64, BB), 256, 0, stream>>>(gram, smax, ssum, PT);
  // GEMM3: xO[b][s][e] = sum_d xC[b,s,d]*PT[b,e,d]  M=2048,N=4096,K=4096,z=2, f32 out
  gemm256<1><<<8 * 16 * BB, 512, LDSB, stream>>>(
      xC, PT, xO, nullptr, 8, 16, DD, DD, (long long)SS * DD, (long long)DD * DD,
      (long long)SS * DD);
  // second softmax -> bf16
  row_softmax_bf16<<<BB * SS, 256, 0, stream>>>(xO, xosm);
  // GEMM4: y5 = bf16( x + silu(xosm @ W4^T) )
  cvt_bf16<<<2048, 256, 0, stream>>>(W[3], wbuf, n4);
  gemm256<2><<<16 * 16, 512, LDSB, stream>>>(
      xosm, wbuf, y5, x, 16, 16, DD, DD, 0LL, 0LL, 0LL);
  // GEMM5: out = y5 @ W5^T  (f32)
  cvt_bf16<<<2048, 256, 0, stream>>>(W[4], wbuf, n4);
  gemm256<1><<<16 * 16, 512, LDSB, stream>>>(
      y5, wbuf, out, nullptr, 16, 16, DD, DD, 0LL, 0LL, 0LL);
}

// Round 4
// 1002.295 us; speedup vs baseline: 1.5933x; 1.0399x over previous
//
// Round 3: single-barrier pipelined K-loop. Ring-4 LDS (BK=32), register
// double-buffered fragments: reads for tile T+1 issue DURING tile T's MFMAs
// (T+1 data already resident => no lgkm coupling). 1 barrier + 1 counted
// vmcnt(4) per K-tile (was 4 barriers). Prefetch window = 2 tiles > HBM lat.
// Predicted: GEMM 149->~85us, MfmaUtil ~60%, total ~650us.
#include <hip/hip_runtime.h>
#include <hip/hip_bf16.h>

#define DD 4096
#define SS 2048
#define BB 2

typedef float f32x4 __attribute__((ext_vector_type(4)));
typedef short bf16x8 __attribute__((ext_vector_type(8)));

__device__ __forceinline__ unsigned short f2b(float f) {
  unsigned int u = __float_as_uint(f);
  u += 0x7fffu + ((u >> 16) & 1u);
  return (unsigned short)(u >> 16);
}
__device__ __forceinline__ float b2f(unsigned short h) {
  return __uint_as_float((unsigned int)h << 16);
}

__device__ __forceinline__ void gll16(const unsigned short* g, unsigned short* l) {
  __builtin_amdgcn_global_load_lds(
      (const __attribute__((address_space(1))) unsigned int*)g,
      (__attribute__((address_space(3))) unsigned int*)l, 16, 0, 0);
}

#define MEMFENCE asm volatile("" ::: "memory")

// ---------------------------------------------------------------------------
// gemm256: C[m][n] = sum_k A[m][k]*B[n][k]; 256x256 tile, BK=32, ring-4 LDS,
// register-double-buffered fragments, 1 barrier + 1 counted vmcnt per K-tile.
// LDS slot: A[16 rowgrps][16][32] then B, st_16x32 swizzle (verified 0-conflict).
// EPI: 0 = bf16 store, 1 = f32 store, 2 = bf16( R + silu(acc) )
// ---------------------------------------------------------------------------

// stage tile (kO = tile*32 elements) into slot base ps
#define STAGE_TILE(ps, kO)                                                     \
  {                                                                            \
    gll16(gA0 + (kO), (unsigned short*)((ps) + wid * 1024));                   \
    gll16(gA1 + (kO), (unsigned short*)((ps) + (wid + 8) * 1024));             \
    gll16(gB0 + (kO), (unsigned short*)((ps) + 16384 + wid * 1024));           \
    gll16(gB1 + (kO), (unsigned short*)((ps) + 16384 + (wid + 8) * 1024));     \
  }

#define TILE_BODY(T, CURB, CURA, NXTB, NXTA)                                   \
  {                                                                            \
    const char* sT = lds + (((T) & 3) * 32768);                                \
    const char* sN = lds + ((((T) + 1) & 3) * 32768);                          \
    if ((T) + 3 < NT) {                                                        \
      char* ps = lds + ((((T) + 3) & 3) * 32768);                              \
      STAGE_TILE(ps, ((T) + 3) * 32);                                          \
    }                                                                          \
    bf16x8 a1_[4];                                                             \
    _Pragma("unroll") for (int m_ = 0; m_ < 4; ++m_)                           \
        a1_[m_] = *(const bf16x8*)(sT + (wm * 8 + 4 + m_) * 1024 + fro);       \
    _Pragma("unroll") for (int n_ = 0; n_ < 4; ++n_)                           \
        NXTB[n_] = *(const bf16x8*)(sN + 16384 + (wn * 4 + n_) * 1024 + fro);  \
    _Pragma("unroll") for (int m_ = 0; m_ < 4; ++m_)                           \
        NXTA[m_] = *(const bf16x8*)(sN + (wm * 8 + m_) * 1024 + fro);          \
    __builtin_amdgcn_s_setprio(1);                                             \
    _Pragma("unroll") for (int m_ = 0; m_ < 4; ++m_)                           \
      _Pragma("unroll") for (int n_ = 0; n_ < 4; ++n_)                         \
        acc[m_][n_] = __builtin_amdgcn_mfma_f32_16x16x32_bf16(                 \
            CURA[m_], CURB[n_], acc[m_][n_], 0, 0, 0);                         \
    _Pragma("unroll") for (int m_ = 0; m_ < 4; ++m_)                           \
      _Pragma("unroll") for (int n_ = 0; n_ < 4; ++n_)                         \
        acc[m_ + 4][n_] = __builtin_amdgcn_mfma_f32_16x16x32_bf16(             \
            a1_[m_], CURB[n_], acc[m_ + 4][n_], 0, 0, 0);                      \
    __builtin_amdgcn_s_setprio(0);                                             \
    if ((T) + 3 < NT) { asm volatile("s_waitcnt vmcnt(4)" ::: "memory"); }     \
    else              { asm volatile("s_waitcnt vmcnt(0)" ::: "memory"); }     \
    __builtin_amdgcn_s_barrier();                                              \
    MEMFENCE;                                                                  \
  }

template <int EPI>
__global__ __launch_bounds__(512, 2)
void gemm256(const unsigned short* __restrict__ A,
             const unsigned short* __restrict__ B,
             void* __restrict__ Cv,
             const float* __restrict__ R,
             int GM, int GN,
             int N, int K,
             long long sA, long long sB, long long sC) {
  extern __shared__ __align__(16) char lds[];
  const int tid = threadIdx.x;
  const int lane = tid & 63;
  const int wid = tid >> 6;
  const int wm = wid >> 2;
  const int wn = wid & 3;

  // T1: bijective XCD swizzle (gridDim.x % 8 == 0 guaranteed by launcher)
  const int nwg = gridDim.x;
  const int cpx = nwg >> 3;
  const int wg = ((int)blockIdx.x & 7) * cpx + ((int)blockIdx.x >> 3);
  const int bz = wg / (GM * GN);
  const int rem = wg - bz * (GM * GN);
  const int bm = rem / GN;
  const int bn = rem - bm * GN;

  const unsigned short* Ab = A + (size_t)bz * sA + (size_t)bm * 256 * K;
  const unsigned short* Bb = B + (size_t)bz * sB + (size_t)bn * 256 * K;

  // T2 staging: inverse-swizzled global source, linear LDS dest
  const int lsw = lane ^ (((lane >> 5) & 1) << 1);
  const int srow = lsw >> 2;
  const int scol = (lsw & 3) * 8;
  const unsigned short* gA0 = Ab + (size_t)(wid * 16 + srow) * K + scol;
  const unsigned short* gA1 = gA0 + (size_t)128 * K;
  const unsigned short* gB0 = Bb + (size_t)(wid * 16 + srow) * K + scol;
  const unsigned short* gB1 = gB0 + (size_t)128 * K;

  // fragment read offset within subtile (bytes), swizzled
  const int r16 = lane & 15;
  const int c16 = ((lane >> 4) * 16) ^ ((r16 & 8) << 2);
  const int fro = r16 * 64 + c16;

  f32x4 acc[8][4] = {};
  const int NT = K >> 5;  // even (64 or 128)

  // ---- prologue: stage tiles 0,1,2
  STAGE_TILE(lds, 0);
  STAGE_TILE(lds + 32768, 32);
  STAGE_TILE(lds + 65536, 64);
  asm volatile("s_waitcnt vmcnt(8)" ::: "memory");  // tile 0 landed (all waves after bar)
  __builtin_amdgcn_s_barrier();
  MEMFENCE;

  bf16x8 c0b[4], c0a[4], c1b[4], c1a[4];
#pragma unroll
  for (int n = 0; n < 4; ++n) c0b[n] = *(const bf16x8*)(lds + 16384 + (wn * 4 + n) * 1024 + fro);
#pragma unroll
  for (int m = 0; m < 4; ++m) c0a[m] = *(const bf16x8*)(lds + (wm * 8 + m) * 1024 + fro);
  asm volatile("s_waitcnt vmcnt(4)" ::: "memory");  // tile 1 landed
  __builtin_amdgcn_s_barrier();
  MEMFENCE;

  for (int T = 0; T < NT; T += 2) {
    TILE_BODY(T, c0b, c0a, c1b, c1a);
    TILE_BODY(T + 1, c1b, c1a, c0b, c0a);
  }

  // ---- epilogue: C/D layout col=lane&15, row=(lane>>4)*4+j
  const int row0 = bm * 256 + wm * 128 + (lane >> 4) * 4;
  const int col0 = bn * 256 + wn * 64 + (lane & 15);

  if constexpr (EPI == 1) {
    float* C = (float*)Cv + (size_t)bz * sC;
#pragma unroll
    for (int m = 0; m < 8; ++m)
#pragma unroll
      for (int j = 0; j < 4; ++j) {
        size_t ro = (size_t)(row0 + m * 16 + j) * N;
#pragma unroll
        for (int n = 0; n < 4; ++n) C[ro + col0 + n * 16] = acc[m][n][j];
      }
  } else if constexpr (EPI == 0) {
    unsigned short* C = (unsigned short*)Cv + (size_t)bz * sC;
#pragma unroll
    for (int m = 0; m < 8; ++m)
#pragma unroll
      for (int j = 0; j < 4; ++j) {
        size_t ro = (size_t)(row0 + m * 16 + j) * N;
#pragma unroll
        for (int n = 0; n < 4; ++n) C[ro + col0 + n * 16] = f2b(acc[m][n][j]);
      }
  } else {
    unsigned short* C = (unsigned short*)Cv + (size_t)bz * sC;
#pragma unroll
    for (int m = 0; m < 8; ++m)
#pragma unroll
      for (int j = 0; j < 4; ++j) {
        size_t ro = (size_t)(row0 + m * 16 + j) * N;
#pragma unroll
        for (int n = 0; n < 4; ++n) {
          size_t idx = ro + col0 + n * 16;
          float v = acc[m][n][j];
          float s = v / (1.f + __expf(-v));
          C[idx] = f2b(R[idx] + s);
        }
      }
  }
}

// ---------------------------------------------------------------------------
__device__ __forceinline__ float wred_max(float v) {
#pragma unroll
  for (int o = 32; o > 0; o >>= 1) v = fmaxf(v, __shfl_xor(v, o, 64));
  return v;
}
__device__ __forceinline__ float wred_sum(float v) {
#pragma unroll
  for (int o = 32; o > 0; o >>= 1) v += __shfl_xor(v, o, 64);
  return v;
}

__global__ __launch_bounds__(256)
void row_stats_bf16(const unsigned short* __restrict__ X, float* __restrict__ smax,
                    float* __restrict__ ssum) {
  const size_t row = blockIdx.x;
  const uint4* p = (const uint4*)(X + row * DD);
  const int t = threadIdx.x;
  uint4 u[2];
  u[0] = p[t];
  u[1] = p[t + 256];
  float fv[16];
#pragma unroll
  for (int q = 0; q < 2; ++q) {
    const unsigned int* w = (const unsigned int*)&u[q];
#pragma unroll
    for (int j = 0; j < 4; ++j) {
      fv[q * 8 + j * 2 + 0] = b2f((unsigned short)(w[j] & 0xFFFFu));
      fv[q * 8 + j * 2 + 1] = b2f((unsigned short)(w[j] >> 16));
    }
  }
  float m = -1e30f;
#pragma unroll
  for (int i = 0; i < 16; ++i) m = fmaxf(m, fv[i]);
  __shared__ float rb[8];
  float wm = wred_max(m);
  if ((t & 63) == 0) rb[t >> 6] = wm;
  __syncthreads();
  const float gm = fmaxf(fmaxf(rb[0], rb[1]), fmaxf(rb[2], rb[3]));
  float s = 0.f;
#pragma unroll
  for (int i = 0; i < 16; ++i) s += __expf(fv[i] - gm);
  float wsum = wred_sum(s);
  if ((t & 63) == 0) rb[4 + (t >> 6)] = wsum;
  __syncthreads();
  if (t == 0) { smax[row] = gm; ssum[row] = rb[4] + rb[5] + rb[6] + rb[7]; }
}

__global__ __launch_bounds__(256)
void exp_transpose_bf16(const unsigned short* __restrict__ X,
                        const float* __restrict__ smax,
                        const float* __restrict__ ssum,
                        unsigned short* __restrict__ PT) {
  const int b = blockIdx.z;
  const int d0 = blockIdx.y * 64;
  const int e0 = blockIdx.x * 64;
  __shared__ unsigned short lt[64][72];
  const int t = threadIdx.x;
  const int tr = t >> 4;
  const int tc = (t & 15) * 4;
  const unsigned short* Xb = X + (size_t)b * DD * DD;
#pragma unroll
  for (int rr = 0; rr < 64; rr += 16) {
    const int dd = rr + tr;
    ushort4 v = *(const ushort4*)&Xb[(size_t)(d0 + dd) * DD + e0 + tc];
    const float mx = smax[(size_t)b * DD + d0 + dd];
    const float inv = 1.f / ssum[(size_t)b * DD + d0 + dd];
    lt[dd][tc + 0] = f2b(__expf(b2f(v.x) - mx) * inv);
    lt[dd][tc + 1] = f2b(__expf(b2f(v.y) - mx) * inv);
    lt[dd][tc + 2] = f2b(__expf(b2f(v.z) - mx) * inv);
    lt[dd][tc + 3] = f2b(__expf(b2f(v.w) - mx) * inv);
  }
  __syncthreads();
  unsigned short* Pb = PT + (size_t)b * DD * DD;
#pragma unroll
  for (int rr = 0; rr < 64; rr += 16) {
    const int ee = rr + tr;
    ushort4 o;
    o.x = lt[tc + 0][ee];
    o.y = lt[tc + 1][ee];
    o.z = lt[tc + 2][ee];
    o.w = lt[tc + 3][ee];
    *(ushort4*)&Pb[(size_t)(e0 + ee) * DD + d0 + tc] = o;
  }
}

__global__ __launch_bounds__(256)
void row_softmax_bf16(const float* __restrict__ X, unsigned short* __restrict__ Y) {
  const size_t row = blockIdx.x;
  const float4* p = (const float4*)(X + row * DD);
  const int t = threadIdx.x;
  float4 v[4];
  float m = -1e30f;
#pragma unroll
  for (int q = 0; q < 4; ++q) {
    v[q] = p[q * 256 + t];
    m = fmaxf(m, fmaxf(fmaxf(v[q].x, v[q].y), fmaxf(v[q].z, v[q].w)));
  }
  __shared__ float rb[8];
  float wm = wred_max(m);
  if ((t & 63) == 0) rb[t >> 6] = wm;
  __syncthreads();
  const float gm = fmaxf(fmaxf(rb[0], rb[1]), fmaxf(rb[2], rb[3]));
  float s = 0.f;
#pragma unroll
  for (int q = 0; q < 4; ++q) {
    v[q].x = __expf(v[q].x - gm); v[q].y = __expf(v[q].y - gm);
    v[q].z = __expf(v[q].z - gm); v[q].w = __expf(v[q].w - gm);
    s += v[q].x + v[q].y + v[q].z + v[q].w;
  }
  float wsum = wred_sum(s);
  if ((t & 63) == 0) rb[4 + (t >> 6)] = wsum;
  __syncthreads();
  const float inv = 1.f / (rb[4] + rb[5] + rb[6] + rb[7]);
  ushort4* yo = (ushort4*)(Y + row * DD);
#pragma unroll
  for (int q = 0; q < 4; ++q) {
    ushort4 o;
    o.x = f2b(v[q].x * inv); o.y = f2b(v[q].y * inv);
    o.z = f2b(v[q].z * inv); o.w = f2b(v[q].w * inv);
    yo[q * 256 + t] = o;
  }
}

__global__ __launch_bounds__(256)
void cvt_bf16(const float* __restrict__ X, unsigned short* __restrict__ Y, size_t n4) {
  size_t i = (size_t)blockIdx.x * 256 + threadIdx.x;
  const size_t stride = (size_t)gridDim.x * 256;
  for (; i < n4; i += stride) {
    float4 v = ((const float4*)X)[i];
    ushort4 o;
    o.x = f2b(v.x); o.y = f2b(v.y); o.z = f2b(v.z); o.w = f2b(v.w);
    ((ushort4*)Y)[i] = o;
  }
}

__global__ void ws_sentinel(float* o, float v) { o[0] = v; }

// ---------------------------------------------------------------------------
extern "C" void kernel_launch(void* const* d_in, const int* in_sizes, int n_in,
                              void* d_out, int out_size, void* d_ws, size_t ws_size,
                              hipStream_t stream) {
  const float* x = (const float*)d_in[0];
  const float* W[5] = {(const float*)d_in[1], (const float*)d_in[2],
                       (const float*)d_in[3], (const float*)d_in[4],
                       (const float*)d_in[5]};
  float* out = (float*)d_out;
  char* ws = (char*)d_ws;

  const size_t WBb = (size_t)DD * DD * 2;
  const size_t NEEDED = 5 * WBb + 2 * (size_t)BB * DD * sizeof(float);
  if (ws_size < NEEDED) {
    ws_sentinel<<<1, 1, 0, stream>>>(out, (float)ws_size);
    return;
  }

  const int LDSB = 131072;
  hipFuncSetAttribute(reinterpret_cast<const void*>(gemm256<0>),
                      hipFuncAttributeMaxDynamicSharedMemorySize, LDSB);
  hipFuncSetAttribute(reinterpret_cast<const void*>(gemm256<1>),
                      hipFuncAttributeMaxDynamicSharedMemorySize, LDSB);
  hipFuncSetAttribute(reinterpret_cast<const void*>(gemm256<2>),
                      hipFuncAttributeMaxDynamicSharedMemorySize, LDSB);

  unsigned short* xbf  = (unsigned short*)(ws + 0 * WBb);
  unsigned short* wbuf = (unsigned short*)(ws + 1 * WBb);
  unsigned short* xAT  = (unsigned short*)(ws + 2 * WBb);
  unsigned short* xBT  = (unsigned short*)(ws + 3 * WBb);
  unsigned short* xC   = (unsigned short*)(ws + 4 * WBb);
  float* smax = (float*)(ws + 5 * WBb);
  float* ssum = smax + (size_t)BB * DD;

  unsigned short* gram = (unsigned short*)d_out;
  unsigned short* PT   = xAT;
  float* xO            = (float*)d_out;
  unsigned short* xosm = xbf;
  unsigned short* y5   = xC;

  const size_t n4 = (size_t)DD * DD / 4;
  cvt_bf16<<<2048, 256, 0, stream>>>(x, xbf, n4);

  // GEMM1a: xAT[b][e][s] = sum_d W1[e,d]*x[b,s,d]
  cvt_bf16<<<2048, 256, 0, stream>>>(W[0], wbuf, n4);
  gemm256<0><<<16 * 8 * BB, 512, LDSB, stream>>>(
      wbuf, xbf, xAT, nullptr, 16, 8, SS, DD, 0LL, (long long)SS * DD, (long long)DD * SS);
  // GEMM1b: xBT
  cvt_bf16<<<2048, 256, 0, stream>>>(W[1], wbuf, n4);
  gemm256<0><<<16 * 8 * BB, 512, LDSB, stream>>>(
      wbuf, xbf, xBT, nullptr, 16, 8, SS, DD, 0LL, (long long)SS * DD, (long long)DD * SS);
  // GEMM1c: xC[n][e] = sum_d x[n,d]*W3[e,d]
  cvt_bf16<<<2048, 256, 0, stream>>>(W[2], wbuf, n4);
  gemm256<0><<<16 * 16, 512, LDSB, stream>>>(
      xbf, wbuf, xC, nullptr, 16, 16, DD, DD, 0LL, 0LL, 0LL);
  // GEMM2 (Gram): gram[b][d][e] = sum_s xAT[b,d,s]*xBT[b,e,s]  K=2048, bf16 out
  gemm256<0><<<16 * 16 * BB, 512, LDSB, stream>>>(
      xAT, xBT, gram, nullptr, 16, 16, DD, SS, (long long)DD * SS, (long long)DD * SS,
      (long long)DD * DD);
  // Gram softmax over e -> transposed bf16 PT[b][e][d]
  row_stats_bf16<<<BB * DD, 256, 0, stream>>>(gram, smax, ssum);
  exp_transpose_bf16<<<dim3(DD / 64, DD / 64, BB), 256, 0, stream>>>(gram, smax, ssum, PT);
  // GEMM3: xO[b][s][e] = sum_d xC[b,s,d]*PT[b,e,d]  (f32 out)
  gemm256<1><<<8 * 16 * BB, 512, LDSB, stream>>>(
      xC, PT, xO, nullptr, 8, 16, DD, DD, (long long)SS * DD, (long long)DD * DD,
      (long long)SS * DD);
  // second softmax -> bf16
  row_softmax_bf16<<<BB * SS, 256, 0, stream>>>(xO, xosm);
  // GEMM4: y5 = bf16( x + silu(xosm @ W4^T) )
  cvt_bf16<<<2048, 256, 0, stream>>>(W[3], wbuf, n4);
  gemm256<2><<<16 * 16, 512, LDSB, stream>>>(
      xosm, wbuf, y5, x, 16, 16, DD, DD, 0LL, 0LL, 0LL);
  // GEMM5: out = y5 @ W5^T  (f32)
  cvt_bf16<<<2048, 256, 0, stream>>>(W[4], wbuf, n4);
  gemm256<1><<<16 * 16, 512, LDSB, stream>>>(
      y5, wbuf, out, nullptr, 16, 16, DD, DD, 0LL, 0LL, 0LL);
}